// Round 13
// baseline (166.045 us; speedup 1.0000x reference)
//
#include <hip/hip_runtime.h>
#include <math.h>

#define NN 512   // set size / rows of feat_x
#define IN 512   // INPUT_DIM
#define HD 256   // HIDDEN_DIM
#define RD 256   // REP_DIM
#define SH 128   // SCORE_HIDDEN

// Branchless erf-GELU, Abramowitz-Stegun 7.1.26 (5-term, |erf err| <= 1.5e-7).
// Used in the g-MLP hidden layer (feeds everything downstream -> keep tight).
__device__ __forceinline__ float gelu_fast(float x){
    const float z  = x * 0.70710678118654752f;
    const float az = fabsf(z);
    const float t  = __builtin_amdgcn_rcpf(fmaf(0.3275911f, az, 1.0f));
    float p = fmaf(1.061405429f, t, -1.453152027f);
    p = fmaf(p, t, 1.421413741f);
    p = fmaf(p, t, -0.284496736f);
    p = fmaf(p, t, 0.254829592f);
    p = p * t;
    const float e = __builtin_amdgcn_exp2f(z * z * -1.4426950408889634f);
    const float E = p * e;                        // erfc(|z|)
    const float one_plus_erf = (x >= 0.0f) ? (2.0f - E) : E;
    return 0.5f * x * one_plus_erf;
}

// u*(1+erf(u/sqrt2)) -- 0.5 folded into caller's weight. A&S 7.1.25 (3-term,
// |erf err| <= 2.5e-5 -> ~1.5e-5 logit error, far under threshold).
// sqrt2 folded: p/sqrt2 = 0.3326725, exp scale = -1/(2 ln2).
__device__ __forceinline__ float gelu2(float u){
    const float az = fabsf(u);
    const float tt = __builtin_amdgcn_rcpf(fmaf(0.3326725f, az, 1.0f));
    const float P  = fmaf(fmaf(0.7478556f, tt, -0.0958798f), tt, 0.3480242f) * tt;
    const float e2 = __builtin_amdgcn_exp2f(u * u * -0.72134752044448170f);
    const float Eq = P * e2;                      // erfc(|u|/sqrt2)
    const float ope = (u >= 0.0f) ? (2.0f - Eq) : Eq;
    return u * ope;
}

// K_REP: fused g-MLP + score-net projections + row norms. 768 blocks
// (3 mats x 256 2-row groups) x 512 thr = exactly 3 blocks/CU balanced,
// 24 waves/CU. 25 KB LDS. Exports r, rT, A_x, BT, and squared row norms.
__global__ __launch_bounds__(512, 6) void k_rep(
    const float* __restrict__ fx, const float* __restrict__ fp, const float* __restrict__ fn,
    const float* __restrict__ w1, const float* __restrict__ b1,
    const float* __restrict__ w2, const float* __restrict__ b2,
    const float* __restrict__ s_w1,
    float* __restrict__ r_x, float* __restrict__ r_p, float* __restrict__ r_n,
    float* __restrict__ rT_p, float* __restrict__ rT_n,
    float* __restrict__ A_x, float* __restrict__ BT_p, float* __restrict__ BT_n,
    float* __restrict__ nx2, float* __restrict__ np2, float* __restrict__ nn2)
{
    __shared__ float2 xs2[IN];        // 4 KB {row0,row1}
    __shared__ float ps[8][2][HD];    // 16 KB K-slice partials (reused as psf[32][SH])
    __shared__ float2 hs2[HD];        // 2 KB
    __shared__ float2 rl2[RD];        // 2 KB
    __shared__ float ab2[2][SH];      // 1 KB
    const int t = threadIdx.x;
    const int mat = blockIdx.x >> 8;
    const int row0 = (blockIdx.x & 255) << 1;
    const float* src = (mat==0) ? fx : (mat==1) ? fp : fn;

    xs2[t] = make_float2(src[row0*IN + t], src[(row0+1)*IN + t]);
    __syncthreads();

    const int cg = t & 63, s = t >> 6;    // 64 float4-colgroups x 8 K-slices
    const int c0 = cg << 2;

    {   // GEMM1: K=512 in 8 slices of 64
        float4 a0 = make_float4(0.f,0.f,0.f,0.f), a1 = a0;
        const float* wp = w1 + (s*64)*HD + c0;
        #pragma unroll 8
        for (int ii=0; ii<64; ii++){
            const float4 w = *(const float4*)wp; wp += HD;
            const float2 x = xs2[s*64 + ii];
            a0.x = fmaf(x.x, w.x, a0.x); a0.y = fmaf(x.x, w.y, a0.y);
            a0.z = fmaf(x.x, w.z, a0.z); a0.w = fmaf(x.x, w.w, a0.w);
            a1.x = fmaf(x.y, w.x, a1.x); a1.y = fmaf(x.y, w.y, a1.y);
            a1.z = fmaf(x.y, w.z, a1.z); a1.w = fmaf(x.y, w.w, a1.w);
        }
        *(float4*)&ps[s][0][c0] = a0;
        *(float4*)&ps[s][1][c0] = a1;
    }
    __syncthreads();

    {   // reduce + bias + GELU -> hs2 (1 output/thread)
        const int j = t >> 8, c = t & 255;
        float v = b1[c];
        #pragma unroll
        for (int ss=0; ss<8; ss++) v += ps[ss][j][c];
        ((float*)hs2)[c*2 + j] = gelu_fast(v);
    }
    __syncthreads();

    {   // GEMM2: K=256 in 8 slices of 32
        float4 a0 = make_float4(0.f,0.f,0.f,0.f), a1 = a0;
        const float* wp = w2 + (s*32)*RD + c0;
        #pragma unroll 8
        for (int ii=0; ii<32; ii++){
            const float4 w = *(const float4*)wp; wp += RD;
            const float2 x = hs2[s*32 + ii];
            a0.x = fmaf(x.x, w.x, a0.x); a0.y = fmaf(x.x, w.y, a0.y);
            a0.z = fmaf(x.x, w.z, a0.z); a0.w = fmaf(x.x, w.w, a0.w);
            a1.x = fmaf(x.y, w.x, a1.x); a1.y = fmaf(x.y, w.y, a1.y);
            a1.z = fmaf(x.y, w.z, a1.z); a1.w = fmaf(x.y, w.w, a1.w);
        }
        *(float4*)&ps[s][0][c0] = a0;
        *(float4*)&ps[s][1][c0] = a1;
    }
    __syncthreads();

    {   // reduce + bias -> rl2 + global r (1 output/thread)
        const int j = t >> 8, c = t & 255;
        float v = b2[c];
        #pragma unroll
        for (int ss=0; ss<8; ss++) v += ps[ss][j][c];
        ((float*)rl2)[c*2 + j] = v;
        float* rout = (mat==0) ? r_x : (mat==1) ? r_p : r_n;
        rout[(row0+j)*RD + c] = v;
    }
    __syncthreads();

    if (t < 128){   // squared row norms: waves 0,1 -> rows 0,1
        const int w = t >> 6, l = t & 63;
        float v = 0.f;
        #pragma unroll
        for (int q=0;q<4;q++){
            const float2 e = rl2[l + 64*q];
            const float ev = w ? e.y : e.x;
            v = fmaf(ev, ev, v);
        }
        #pragma unroll
        for (int off=32; off>=1; off>>=1) v += __shfl_xor(v, off);
        if (l==0){
            float* nrm = (mat==0) ? nx2 : (mat==1) ? np2 : nn2;
            nrm[row0 + w] = v;
        }
    }
    if (mat && t < 256){   // transposed rep copy rT[r][m]
        float* rT = (mat==1) ? rT_p : rT_n;
        *(float2*)&rT[t*NN + row0] = rl2[t];
    }

    {   // score-net projection: 128 cols, K=256 in 16 slices of 16
        const int cg2 = t & 31, s2 = t >> 5;
        const int cc0 = cg2 << 2;
        const float sgn = (mat==0) ? -1.0f : 1.0f;
        const int base1 = (mat==0) ? 0 : 256;
        const float* p1 = s_w1 + (base1 + s2*16)*SH + cc0;
        const float* p3 = s_w1 + (512   + s2*16)*SH + cc0;
        float4 a0 = make_float4(0.f,0.f,0.f,0.f), a1 = a0;
        #pragma unroll 8
        for (int ii=0; ii<16; ii++){
            const float4 wa = *(const float4*)p1; p1 += SH;
            const float4 wd = *(const float4*)p3; p3 += SH;
            float4 w;
            w.x = fmaf(sgn, wd.x, wa.x);
            w.y = fmaf(sgn, wd.y, wa.y);
            w.z = fmaf(sgn, wd.z, wa.z);
            w.w = fmaf(sgn, wd.w, wa.w);
            const float2 x = rl2[s2*16 + ii];
            a0.x = fmaf(x.x, w.x, a0.x); a0.y = fmaf(x.x, w.y, a0.y);
            a0.z = fmaf(x.x, w.z, a0.z); a0.w = fmaf(x.x, w.w, a0.w);
            a1.x = fmaf(x.y, w.x, a1.x); a1.y = fmaf(x.y, w.y, a1.y);
            a1.z = fmaf(x.y, w.z, a1.z); a1.w = fmaf(x.y, w.w, a1.w);
        }
        float* psf = &ps[0][0][0];   // reuse as [32][SH]
        *(float4*)&psf[(s2*2+0)*SH + cc0] = a0;
        *(float4*)&psf[(s2*2+1)*SH + cc0] = a1;
    }
    __syncthreads();

    if (t < 256){   // reduce 16 slices: 2 rows x 128 cols
        const float* psf = &ps[0][0][0];
        const int j = t >> 7, c = t & 127;
        float v = 0.f;
        #pragma unroll
        for (int ss=0; ss<16; ss++) v += psf[(ss*2+j)*SH + c];
        if (mat==0) A_x[(row0+j)*SH + c] = v;
        else        ab2[j][c] = v;
    }
    __syncthreads();
    if (mat && t < 128){   // BT[k][m]
        float* BT = (mat==1) ? BT_p : BT_n;
        *(float2*)&BT[t*NN + row0] = make_float2(ab2[0][t], ab2[1][t]);
    }
}

// K_SD: distances + logits + exp + fused partial einsum. 2048 blocks
// (set x 256 2-row ntiles x 4 128-m mtiles) x 256 thr = 8 blocks/CU.
// Norms imported from k_rep (no per-tile recompute); 3-term gelu.
__global__ __launch_bounds__(256) void k_sd(
    const float* __restrict__ r_x, const float* __restrict__ rT_p, const float* __restrict__ rT_n,
    const float* __restrict__ A_x, const float* __restrict__ BT_p, const float* __restrict__ BT_n,
    const float* __restrict__ r_p, const float* __restrict__ r_n,
    const float* __restrict__ nx2, const float* __restrict__ np2, const float* __restrict__ nn2,
    const float* __restrict__ s_w1, const float* __restrict__ s_b1,
    const float* __restrict__ s_w2,
    float* __restrict__ psum, float* __restrict__ Spart)
{
    __shared__ float2 xs2[RD];        // 2 KB: {x0,x1}[r]
    __shared__ float4 cmb[SH];        // 2 KB: {A0+b1, A1+b1, wn, 0.5*w2}
    __shared__ float pda[2][128];     // stride-4B partials (conflict-free)
    __shared__ float pdb[2][128];
    __shared__ float ny2v[128];
    __shared__ float2 evb[128];       // 1 KB: per-m {ev0, ev1}
    __shared__ float ssum[2][2];
    const int t = threadIdx.x;
    const int set = blockIdx.x >> 10;
    const int rem = blockIdx.x & 1023;
    const int n0 = (rem >> 2) << 1;
    const int mt = rem & 3;
    const int mbase = mt << 7;
    const int tm = t & 127, kh = t >> 7;   // kh uniform per wave
    const int m = mbase + tm;
    const float* yT = set ? rT_n : rT_p;
    const float* BT = set ? BT_n : BT_p;

    xs2[t] = make_float2(r_x[n0*RD + t], r_x[(n0+1)*RD + t]);
    if (t < SH){
        const float b1v = s_b1[t];
        cmb[t] = make_float4(A_x[n0*SH + t] + b1v,
                             A_x[(n0+1)*SH + t] + b1v,
                             s_w1[768*SH + t],
                             0.5f * s_w2[t]);
        ny2v[t] = (set ? nn2 : np2)[mbase + t];
    }
    const float nxa = nx2[n0];         // wave-uniform -> scalar loads
    const float nxb = nx2[n0 + 1];
    __syncthreads();

    // phase 1: dots over this wave's r-half (coalesced column-major loads)
    float d0=0.f, d1=0.f;
    {
        const float* yp = yT + (kh << 7)*NN + m;
        #pragma unroll 16
        for (int rr=0; rr<128; rr++){
            const float y = yp[rr*NN];
            const float2 xv = xs2[(kh << 7) + rr];
            d0 = fmaf(xv.x, y, d0);
            d1 = fmaf(xv.y, y, d1);
        }
    }
    pda[kh][tm] = d0; pdb[kh][tm] = d1;
    __syncthreads();
    d0 += pda[1-kh][tm]; d1 += pdb[1-kh][tm];
    const float nyc = ny2v[tm];
    const float dn0 = sqrtf(fmaxf(fmaf(-2.f, d0, nxa + nyc), 0.f));
    const float dn1 = sqrtf(fmaxf(fmaf(-2.f, d1, nxb + nyc), 0.f));

    // phase 2: logits over this wave's k-half (coalesced BT loads)
    float acc0 = 0.f, acc1 = 0.f;
    {
        const float* bp = BT + (kh << 6)*NN + m;
        #pragma unroll 4
        for (int kk=0; kk<64; kk++){
            const float b = bp[kk*NN];
            const float4 c = cmb[(kh << 6) + kk];
            const float u0 = fmaf(dn0, c.z, c.x + b);
            const float u1 = fmaf(dn1, c.z, c.y + b);
            acc0 = fmaf(c.w, gelu2(u0), acc0);
            acc1 = fmaf(c.w, gelu2(u1), acc1);
        }
    }
    __syncthreads();                       // partner done reading phase-1 pd
    pda[kh][tm] = acc0; pdb[kh][tm] = acc1;
    __syncthreads();
    if (kh == 0){
        // s_b2 omitted (softmax shift-invariant); no max pass (logits O(1))
        const float ev0 = __builtin_amdgcn_exp2f((acc0 + pda[1][tm]) * 1.4426950408889634f);
        const float ev1 = __builtin_amdgcn_exp2f((acc1 + pdb[1][tm]) * 1.4426950408889634f);
        evb[tm] = make_float2(ev0, ev1);
        float v0 = ev0, v1 = ev1;
        #pragma unroll
        for (int off=32; off>=1; off>>=1){ v0 += __shfl_xor(v0, off); v1 += __shfl_xor(v1, off); }
        if ((t & 63) == 0){
            ssum[tm >> 6][0] = v0;
            ssum[tm >> 6][1] = v1;
        }
    }
    __syncthreads();
    if (t < 2)
        Spart[(set*4 + mt)*NN + n0 + t] = ssum[0][t] + ssum[1][t];

    // fused partial einsum: psum[set][mt][n0+j][c] = Sum_{m in tile} ev_j * r_y[m][c]
    {
        const float* ry = (set ? r_n : r_p) + mbase*RD + t;   // coalesced in c=t
        float a0 = 0.f, a1 = 0.f;
        #pragma unroll 8
        for (int mm=0; mm<128; mm++){
            const float rv = ry[mm*RD];
            const float2 w = evb[mm];        // ds_read_b64 broadcast
            a0 = fmaf(w.x, rv, a0);
            a1 = fmaf(w.y, rv, a1);
        }
        float* P = psum + ((set*4 + mt)*NN + n0)*RD;
        P[t]      = a0;
        P[RD + t] = a1;
    }
}

// K_FIN: dv = Sum_mt psum_p/Sp - Sum_mt psum_n/Sn; out = dv @ out_w.
// 1024 blocks (256 n-pairs x 4 col-tiles) x 256 thr = 4/CU, 16 waves/CU.
__global__ __launch_bounds__(256) void k_fin(
    const float* __restrict__ psum, const float* __restrict__ Spart,
    const float* __restrict__ out_w, float* __restrict__ out)
{
    __shared__ float dv[2][RD];   // 2 KB
    const int t = threadIdx.x;
    const int np = blockIdx.x >> 2, ct = blockIdx.x & 3;
    const int n0 = np << 1;
    const int cb = ct << 7;

    #pragma unroll
    for (int rep=0; rep<2; rep++){   // dv: 512 entries, 2/thread
        const int idx = rep*256 + t;
        const int j = idx >> 8, c = idx & 255;
        const int n = n0 + j;
        float Sp = 0.f, Sn = 0.f;
        #pragma unroll
        for (int q=0;q<4;q++){
            Sp += Spart[q*NN + n];
            Sn += Spart[(4+q)*NN + n];
        }
        float vp = 0.f, vn = 0.f;
        #pragma unroll
        for (int q=0;q<4;q++){
            vp += psum[(q*NN + n)*RD + c];
            vn += psum[((4+q)*NN + n)*RD + c];
        }
        dv[j][c] = vp * (1.0f/Sp) - vn * (1.0f/Sn);
    }
    __syncthreads();

    {   // out[j][cb+cc] = Sum_r dv[j][r]*out_w[r][cb+cc]
        const int j = t >> 7, cc = t & 127;
        const int col = cb + cc;
        float o = 0.f;
        const float* wo = out_w + col;
        #pragma unroll 8
        for (int r=0; r<RD; r++){ o = fmaf(dv[j][r], *wo, o); wo += IN; }
        out[(n0+j)*IN + col] = o;
    }
}

extern "C" void kernel_launch(void* const* d_in, const int* in_sizes, int n_in,
                              void* d_out, int out_size, void* d_ws, size_t ws_size,
                              hipStream_t stream)
{
    const float* fx  = (const float*)d_in[0];
    const float* fp  = (const float*)d_in[1];
    const float* fn  = (const float*)d_in[2];
    const float* gw1 = (const float*)d_in[3];
    const float* gb1 = (const float*)d_in[4];
    const float* gw2 = (const float*)d_in[5];
    const float* gb2 = (const float*)d_in[6];
    const float* ow  = (const float*)d_in[7];
    const float* sw1 = (const float*)d_in[8];
    const float* sb1 = (const float*)d_in[9];
    const float* sw2 = (const float*)d_in[10];
    float* out = (float*)d_out;

    float* ws   = (float*)d_ws;
    float* r_x  = ws;               // 512*256 row-major
    float* r_p  = r_x  + 131072;
    float* r_n  = r_p  + 131072;
    float* rT_p = r_n  + 131072;    // 256*512 column-major
    float* rT_n = rT_p + 131072;
    float* A_x  = rT_n + 131072;    // 512*128 row-major [n][k]
    float* BT_p = A_x  + 65536;     // 128*512 column-major [k][m]
    float* BT_n = BT_p + 65536;
    float* Spar = BT_n + 65536;     // 2*4*512
    float* nx2  = Spar + 4096;      // 512
    float* np2  = nx2  + 512;
    float* nn2  = np2  + 512;
    float* psum = nn2  + 512;       // 2*4*512*256 (4 MB)

    hipLaunchKernelGGL(k_rep, dim3(768), dim3(512), 0, stream,
                       fx, fp, fn, gw1, gb1, gw2, gb2, sw1,
                       r_x, r_p, r_n, rT_p, rT_n, A_x, BT_p, BT_n,
                       nx2, np2, nn2);
    hipLaunchKernelGGL(k_sd, dim3(2048), dim3(256), 0, stream,
                       r_x, rT_p, rT_n, A_x, BT_p, BT_n, r_p, r_n,
                       nx2, np2, nn2, sw1, sb1, sw2, psum, Spar);
    hipLaunchKernelGGL(k_fin, dim3(1024), dim3(256), 0, stream,
                       psum, Spar, ow, out);
}